// Round 3
// baseline (281.773 us; speedup 1.0000x reference)
//
#include <hip/hip_runtime.h>
#include <hip/hip_bf16.h>

#define NN 8192
#define NE 262144

typedef __attribute__((ext_vector_type(8))) short bf16x8;
typedef __attribute__((ext_vector_type(4))) float f32x4;

// ---------------- CSR build ----------------
__global__ __launch_bounds__(256) void k_init(float* __restrict__ deg, int* __restrict__ counts,
                                              int* __restrict__ cnt2) {
  int i = blockIdx.x * 256 + threadIdx.x;
  if (i < NN) { deg[i] = 1.0f; counts[i] = 0; cnt2[i] = 0; }
}

__global__ __launch_bounds__(256) void k_count(const int* __restrict__ ei, const float* __restrict__ w,
                                               float* __restrict__ deg, int* __restrict__ counts) {
  int e = blockIdx.x * 256 + threadIdx.x;
  if (e < NE) {
    int c = ei[NE + e];
    atomicAdd(&deg[c], w[e]);
    atomicAdd(&counts[c], 1);
  }
}

__global__ __launch_bounds__(1024) void k_scan(const int* __restrict__ counts, int* __restrict__ offs) {
  __shared__ int part[1024];
  int t = threadIdx.x;
  int base = t * 8;
  int local[8];
  int s = 0;
#pragma unroll
  for (int j = 0; j < 8; ++j) { local[j] = counts[base + j]; s += local[j]; }
  part[t] = s;
  __syncthreads();
  for (int off = 1; off < 1024; off <<= 1) {
    int v = (t >= off) ? part[t - off] : 0;
    __syncthreads();
    part[t] += v;
    __syncthreads();
  }
  int run = (t > 0) ? part[t - 1] : 0;
#pragma unroll
  for (int j = 0; j < 8; ++j) { offs[base + j] = run; run += local[j]; }
  if (t == 1023) offs[NN] = run;
}

__global__ __launch_bounds__(256) void k_scatter(const int* __restrict__ ei, const float* __restrict__ w,
                                                 const float* __restrict__ deg, const int* __restrict__ offs,
                                                 int* __restrict__ cnt2, int* __restrict__ csr_row,
                                                 float* __restrict__ csr_val) {
  int e = blockIdx.x * 256 + threadIdx.x;
  if (e < NE) {
    int r = ei[e], c = ei[NE + e];
    int slot = offs[c] + atomicAdd(&cnt2[c], 1);
    csr_row[slot] = r;
    csr_val[slot] = rsqrtf(deg[r]) * w[e] * rsqrtf(deg[c]);
  }
}

// ---------------- split fp32 -> hi/lo bf16 (row-major, same layout) ----------------
__global__ __launch_bounds__(256) void k_splitX(const float* __restrict__ x,
                                                __hip_bfloat16* __restrict__ xh,
                                                __hip_bfloat16* __restrict__ xl) {
  size_t i = ((size_t)blockIdx.x * 256 + threadIdx.x) * 4;
  f32x4 v = *(const f32x4*)(x + i);
#pragma unroll
  for (int j = 0; j < 4; ++j) {
    __hip_bfloat16 h = __float2bfloat16(v[j]);
    xh[i + j] = h;
    xl[i + j] = __float2bfloat16(v[j] - __bfloat162float(h));
  }
}

// ---------------- split + transpose W[K,N] -> WhT/WlT [N,K] ----------------
__global__ __launch_bounds__(256) void k_splitW(const float* __restrict__ W,
                                                __hip_bfloat16* __restrict__ WhT,
                                                __hip_bfloat16* __restrict__ WlT, int K, int Nc) {
  int idx = blockIdx.x * 256 + threadIdx.x;
  if (idx < K * Nc) {
    int k = idx / Nc, n = idx - k * Nc;
    float v = W[idx];
    __hip_bfloat16 h = __float2bfloat16(v);
    WhT[(size_t)n * K + k] = h;
    WlT[(size_t)n * K + k] = __float2bfloat16(v - __bfloat162float(h));
  }
}

// ---------------- concat heads: Wm,Ws [256,64] -> WcatT pair [128,256]; bcat ----------------
__global__ __launch_bounds__(256) void k_splitWcat(const float* __restrict__ Wm, const float* __restrict__ Wsw,
                                                   const float* __restrict__ bm, const float* __restrict__ bsv,
                                                   __hip_bfloat16* __restrict__ WhT,
                                                   __hip_bfloat16* __restrict__ WlT,
                                                   float* __restrict__ bcat) {
  int idx = blockIdx.x * 256 + threadIdx.x;   // < 128*256
  int n = idx >> 8, k = idx & 255;
  float v = (n < 64) ? Wm[k * 64 + n] : Wsw[k * 64 + (n - 64)];
  __hip_bfloat16 h = __float2bfloat16(v);
  WhT[idx] = h;
  WlT[idx] = __float2bfloat16(v - __bfloat162float(h));
  if (blockIdx.x == 0 && threadIdx.x < 128)
    bcat[threadIdx.x] = (threadIdx.x < 64) ? bm[threadIdx.x] : bsv[threadIdx.x - 64];
}

// ---------------- split-bf16 MFMA GEMM: C[M,Nc] = A[M,K] @ B[K,Nc], B given as B^T pairs ----------------
__global__ __launch_bounds__(256) void k_gemm_mfma(const short* __restrict__ Ah, const short* __restrict__ Al,
                                                   const short* __restrict__ BhT, const short* __restrict__ BlT,
                                                   float* __restrict__ C, int K, int Nc) {
  int m0 = blockIdx.y * 64, n0 = blockIdx.x * 64;
  int wv = threadIdx.x >> 6, lane = threadIdx.x & 63;
  int wr = wv >> 1, wc = wv & 1;               // 2x2 waves, each a 32x32 quadrant
  int lr = lane & 15, lk8 = (lane >> 4) << 3;
  int arow = m0 + wr * 32 + lr;
  int bcol = n0 + wc * 32 + lr;                // row index into B^T
  f32x4 acc[2][2] = {};
  for (int k0 = 0; k0 < K; k0 += 32) {
    bf16x8 ah[2], al[2], bh[2], bl[2];
#pragma unroll
    for (int rb = 0; rb < 2; ++rb) {
      size_t o = (size_t)(arow + rb * 16) * K + k0 + lk8;
      ah[rb] = *(const bf16x8*)(Ah + o);
      al[rb] = *(const bf16x8*)(Al + o);
    }
#pragma unroll
    for (int cb = 0; cb < 2; ++cb) {
      size_t o = (size_t)(bcol + cb * 16) * K + k0 + lk8;
      bh[cb] = *(const bf16x8*)(BhT + o);
      bl[cb] = *(const bf16x8*)(BlT + o);
    }
#pragma unroll
    for (int rb = 0; rb < 2; ++rb)
#pragma unroll
      for (int cb = 0; cb < 2; ++cb) {
        f32x4 c = acc[rb][cb];
        c = __builtin_amdgcn_mfma_f32_16x16x32_bf16(ah[rb], bh[cb], c, 0, 0, 0);
        c = __builtin_amdgcn_mfma_f32_16x16x32_bf16(ah[rb], bl[cb], c, 0, 0, 0);
        c = __builtin_amdgcn_mfma_f32_16x16x32_bf16(al[rb], bh[cb], c, 0, 0, 0);
        acc[rb][cb] = c;
      }
  }
  int orow = m0 + wr * 32 + ((lane >> 4) << 2);
  int ocol = n0 + wc * 32 + (lane & 15);
#pragma unroll
  for (int rb = 0; rb < 2; ++rb)
#pragma unroll
    for (int cb = 0; cb < 2; ++cb)
#pragma unroll
      for (int r = 0; r < 4; ++r)
        C[(size_t)(orow + rb * 16 + r) * Nc + ocol + cb * 16] = acc[rb][cb][r];
}

// ---------------- CSR aggregation + bias + relu; optional split-bf16 output ----------------
template <int D, bool SPLIT>
__global__ __launch_bounds__(256) void k_agg(const float* __restrict__ t, const float* __restrict__ deg,
                                             const int* __restrict__ csr_row, const float* __restrict__ csr_val,
                                             const int* __restrict__ offs, const float* __restrict__ bias,
                                             float* __restrict__ outf,
                                             __hip_bfloat16* __restrict__ outh,
                                             __hip_bfloat16* __restrict__ outl) {
  constexpr int V = D / 64;
  __shared__ int   srow[256];
  __shared__ float sval[256];
  __shared__ float sacc[4][D];
  int c = blockIdx.x;
  int tid = threadIdx.x;
  int w = tid >> 6, lane = tid & 63;
  int d0 = lane * V;
  float acc[V];
#pragma unroll
  for (int j = 0; j < V; ++j) acc[j] = 0.0f;
  int s0 = offs[c], s1 = offs[c + 1];
  for (int base = s0; base < s1; base += 256) {
    int cnt = s1 - base; if (cnt > 256) cnt = 256;
    __syncthreads();
    if (tid < cnt) { srow[tid] = csr_row[base + tid]; sval[tid] = csr_val[base + tid]; }
    __syncthreads();
    for (int s = w; s < cnt; s += 4) {
      int r = srow[s];
      float v = sval[s];
      const float* p = t + (size_t)r * D + d0;
      if constexpr (V == 4) {
        float4 pv = *(const float4*)p;
        acc[0] = fmaf(v, pv.x, acc[0]);
        acc[1] = fmaf(v, pv.y, acc[1]);
        acc[2] = fmaf(v, pv.z, acc[2]);
        acc[3] = fmaf(v, pv.w, acc[3]);
      } else {
        float2 pv = *(const float2*)p;
        acc[0] = fmaf(v, pv.x, acc[0]);
        acc[1] = fmaf(v, pv.y, acc[1]);
      }
    }
  }
#pragma unroll
  for (int j = 0; j < V; ++j) sacc[w][d0 + j] = acc[j];
  __syncthreads();
  if (tid < 64) {
    float di = rsqrtf(deg[c]);
    float selfw = di * di;
#pragma unroll
    for (int j = 0; j < V; ++j) {
      int d = tid * V + j;
      float a = sacc[0][d] + sacc[1][d] + sacc[2][d] + sacc[3][d];
      a = fmaf(selfw, t[(size_t)c * D + d], a);
      a = fmaxf(a + bias[d], 0.0f);
      if constexpr (SPLIT) {
        __hip_bfloat16 h = __float2bfloat16(a);
        outh[(size_t)c * D + d] = h;
        outl[(size_t)c * D + d] = __float2bfloat16(a - __bfloat162float(h));
      } else {
        outf[(size_t)c * D + d] = a;
      }
    }
  }
}

// ---------------- z = noise*exp(log_std)+mean, split bf16 ----------------
__global__ __launch_bounds__(256) void k_z(const float* __restrict__ gms, const float* __restrict__ noise,
                                           __hip_bfloat16* __restrict__ zh, __hip_bfloat16* __restrict__ zl) {
  int idx = blockIdx.x * 256 + threadIdx.x;
  int i = idx >> 6, k = idx & 63;
  float mean = gms[(size_t)i * 128 + k];
  float ls = gms[(size_t)i * 128 + 64 + k];
  float z = noise[idx] * __expf(ls) + mean;
  __hip_bfloat16 h = __float2bfloat16(z);
  zh[idx] = h;
  zl[idx] = __float2bfloat16(z - __bfloat162float(h));
}

// ---------------- final: triu(sigmoid(z z^T), 1), split-bf16 MFMA ----------------
__global__ __launch_bounds__(256) void k_final(const short* __restrict__ zh, const short* __restrict__ zl,
                                               float* __restrict__ out) {
  int ti = blockIdx.y, tj = blockIdx.x;
  int ri0 = ti * 128, cj0 = tj * 128;
  if (tj < ti) {
    f32x4 zz = {};
    int tr = threadIdx.x >> 5;
    int tc = (threadIdx.x & 31) << 2;
    float* base = out + (size_t)(ri0 + tr) * NN + cj0 + tc;
#pragma unroll
    for (int rr = 0; rr < 128; rr += 8)
      *(f32x4*)(base + (size_t)rr * NN) = zz;
    return;
  }
  int wv = threadIdx.x >> 6;
  int lane = threadIdx.x & 63;
  int wr = wv >> 1, wc = wv & 1;
  int lr = lane & 15;
  int lk = (lane >> 4) << 3;
  int arow = ri0 + wr * 64 + lr;
  int brow = cj0 + wc * 64 + lr;

  bf16x8 ah[4][2], al[4][2];
#pragma unroll
  for (int rb = 0; rb < 4; ++rb)
#pragma unroll
    for (int ks = 0; ks < 2; ++ks) {
      int o = (arow + rb * 16) * 64 + ks * 32 + lk;
      ah[rb][ks] = *(const bf16x8*)(zh + o);
      al[rb][ks] = *(const bf16x8*)(zl + o);
    }
  f32x4 acc[4][4] = {};
#pragma unroll
  for (int cb = 0; cb < 4; ++cb) {
    bf16x8 bh[2], bl[2];
#pragma unroll
    for (int ks = 0; ks < 2; ++ks) {
      int o = (brow + cb * 16) * 64 + ks * 32 + lk;
      bh[ks] = *(const bf16x8*)(zh + o);
      bl[ks] = *(const bf16x8*)(zl + o);
    }
#pragma unroll
    for (int rb = 0; rb < 4; ++rb) {
      f32x4 c = acc[rb][cb];
#pragma unroll
      for (int ks = 0; ks < 2; ++ks) {
        c = __builtin_amdgcn_mfma_f32_16x16x32_bf16(ah[rb][ks], bh[ks], c, 0, 0, 0);
        c = __builtin_amdgcn_mfma_f32_16x16x32_bf16(ah[rb][ks], bl[ks], c, 0, 0, 0);
        c = __builtin_amdgcn_mfma_f32_16x16x32_bf16(al[rb][ks], bh[ks], c, 0, 0, 0);
      }
      acc[rb][cb] = c;
    }
  }
  int orow = ri0 + wr * 64 + ((lane >> 4) << 2);
  int ocol = cj0 + wc * 64 + (lane & 15);
#pragma unroll
  for (int rb = 0; rb < 4; ++rb)
#pragma unroll
    for (int cb = 0; cb < 4; ++cb)
#pragma unroll
      for (int r = 0; r < 4; ++r) {
        int row = orow + rb * 16 + r;
        int col = ocol + cb * 16;
        float v = acc[rb][cb][r];
        float sg = 1.0f / (1.0f + __expf(-v));
        out[(size_t)row * NN + col] = (col > row) ? sg : 0.0f;
      }
}

extern "C" void kernel_launch(void* const* d_in, const int* in_sizes, int n_in,
                              void* d_out, int out_size, void* d_ws, size_t ws_size,
                              hipStream_t stream) {
  (void)in_sizes; (void)n_in; (void)out_size; (void)ws_size;
  const float* x     = (const float*)d_in[0];
  const int*   ei    = (const int*)d_in[1];
  const float* ew    = (const float*)d_in[2];
  const float* noise = (const float*)d_in[3];
  const float* W1    = (const float*)d_in[4];
  const float* b1    = (const float*)d_in[5];
  const float* W2    = (const float*)d_in[6];
  const float* b2    = (const float*)d_in[7];
  const float* Wm    = (const float*)d_in[8];
  const float* bm    = (const float*)d_in[9];
  const float* Wsw   = (const float*)d_in[10];
  const float* bsv   = (const float*)d_in[11];
  float* out = (float*)d_out;

  char* wsb = (char*)d_ws;
  size_t off = 0;
  auto bump = [&](size_t bytes) -> void* {
    void* p = wsb + off;
    off += (bytes + 255) & ~(size_t)255;
    return p;
  };
  float* deg     = (float*)bump((size_t)NN * 4);
  int*   counts  = (int*)bump((size_t)NN * 4);
  int*   offs    = (int*)bump((size_t)(NN + 1) * 4);
  int*   cnt2    = (int*)bump((size_t)NN * 4);
  int*   csr_row = (int*)bump((size_t)NE * 4);
  float* csr_val = (float*)bump((size_t)NE * 4);
  // x split pair (8 MB each); later reused for h2 split pair (4 MB each)
  __hip_bfloat16* xh = (__hip_bfloat16*)bump((size_t)NN * 512 * 2);
  __hip_bfloat16* xl = (__hip_bfloat16*)bump((size_t)NN * 512 * 2);
  float* bufA    = (float*)bump((size_t)NN * 256 * 4);      // GEMM outputs (fp32)
  __hip_bfloat16* h1h = (__hip_bfloat16*)bump((size_t)NN * 256 * 2);  // also bufG (fp32 8192x128) later
  __hip_bfloat16* h1l = (__hip_bfloat16*)bump((size_t)NN * 256 * 2);
  __hip_bfloat16* W1hT = (__hip_bfloat16*)bump((size_t)256 * 512 * 2);
  __hip_bfloat16* W1lT = (__hip_bfloat16*)bump((size_t)256 * 512 * 2);
  __hip_bfloat16* W2hT = (__hip_bfloat16*)bump((size_t)256 * 256 * 2);
  __hip_bfloat16* W2lT = (__hip_bfloat16*)bump((size_t)256 * 256 * 2);
  __hip_bfloat16* WchT = (__hip_bfloat16*)bump((size_t)128 * 256 * 2);
  __hip_bfloat16* WclT = (__hip_bfloat16*)bump((size_t)128 * 256 * 2);
  float* bcat    = (float*)bump((size_t)128 * 4);
  __hip_bfloat16* zh = (__hip_bfloat16*)bump((size_t)NN * 64 * 2);
  __hip_bfloat16* zl = (__hip_bfloat16*)bump((size_t)NN * 64 * 2);

  __hip_bfloat16* h2h = xh;                 // alias: x pair dead after GEMM1
  __hip_bfloat16* h2l = xl;
  float* bufG = (float*)h1h;                // alias: h1 pair dead after GEMM2 (4 MB fits)

  // CSR build
  k_init<<<NN / 256, 256, 0, stream>>>(deg, counts, cnt2);
  k_count<<<NE / 256, 256, 0, stream>>>(ei, ew, deg, counts);
  k_scan<<<1, 1024, 0, stream>>>(counts, offs);
  k_scatter<<<NE / 256, 256, 0, stream>>>(ei, ew, deg, offs, cnt2, csr_row, csr_val);

  // weight prep
  k_splitX<<<NN * 512 / 4 / 256, 256, 0, stream>>>(x, xh, xl);
  k_splitW<<<512, 256, 0, stream>>>(W1, W1hT, W1lT, 512, 256);
  k_splitW<<<256, 256, 0, stream>>>(W2, W2hT, W2lT, 256, 256);
  k_splitWcat<<<128, 256, 0, stream>>>(Wm, Wsw, bm, bsv, WchT, WclT, bcat);

  // layer 1: h1 = relu(Agg(x@W1) + b1)  (split output)
  k_gemm_mfma<<<dim3(4, 128), 256, 0, stream>>>((const short*)xh, (const short*)xl,
                                                (const short*)W1hT, (const short*)W1lT, bufA, 512, 256);
  k_agg<256, true><<<NN, 256, 0, stream>>>(bufA, deg, csr_row, csr_val, offs, b1, nullptr, h1h, h1l);
  // layer 2: h2 = relu(Agg(h1@W2) + b2)  (split output)
  k_gemm_mfma<<<dim3(4, 128), 256, 0, stream>>>((const short*)h1h, (const short*)h1l,
                                                (const short*)W2hT, (const short*)W2lT, bufA, 256, 256);
  k_agg<256, true><<<NN, 256, 0, stream>>>(bufA, deg, csr_row, csr_val, offs, b2, nullptr, h2h, h2l);
  // heads: [mean|log_std] = relu(Agg(h2@[Wm|Ws]) + bcat)  (fp32 output)
  k_gemm_mfma<<<dim3(2, 128), 256, 0, stream>>>((const short*)h2h, (const short*)h2l,
                                                (const short*)WchT, (const short*)WclT, bufA, 256, 128);
  k_agg<128, false><<<NN, 256, 0, stream>>>(bufA, deg, csr_row, csr_val, offs, bcat, bufG, nullptr, nullptr);
  // z (split bf16)
  k_z<<<NN * 64 / 256, 256, 0, stream>>>(bufG, noise, zh, zl);
  // out = triu(sigmoid(z z^T), 1)
  k_final<<<dim3(64, 64), 256, 0, stream>>>((const short*)zh, (const short*)zl, out);
}